// Round 13
// baseline (89349.731 us; speedup 1.0000x reference)
//
#include <hip/hip_runtime.h>
#include <hip/hip_bf16.h>
#include <stdint.h>
#include <stddef.h>

// ---------------- problem constants ----------------
#define T_STEPS 256
#define CLEN    16
#define HWD     1024
#define HCD     512
#define VWORD   50257
#define VCHAR   62

#define NWG   80     // 16 char WGs + 64 word WGs, all co-resident (<=256 CUs)
#define NTHR  256

typedef __attribute__((ext_vector_type(4))) float f4;
typedef __attribute__((ext_vector_type(8))) unsigned short us8;
typedef __attribute__((ext_vector_type(4))) int i4v;
typedef __attribute__((ext_vector_type(2))) int i2v;

// ---------------- workspace layout (int-indexed exchange region, sc0 sc1) ----------------
enum : size_t {
  I_PUB = 0,                         // pub2[2][1024][2]  (h0[512]+h1[512] per parity)
  I_HW0 = 4096,                      // hw02[2][1024][2]
  I_HW1 = 8192,                      // hw12[2][1024][2]
  I_C1H = 12288,                     // c1hist[256][512][2] append-only
  I_END = I_C1H + (size_t)256 * 512 * 2,   // 274432 ints
};
// float-indexed region after the pairs:
enum : size_t {
  WS_G    = I_END,
  WS_XW   = WS_G + 256,
  WS_Y    = WS_XW + (size_t)T_STEPS * HWD,
  WS_PRE0 = WS_Y + (size_t)T_STEPS * HWD,
  WS_B1   = WS_PRE0 + (size_t)VCHAR * 2048,
  WS_BW0  = WS_B1 + 2048,
  WS_BW1  = WS_BW0 + 4096,
  WS_BF   = WS_BW1 + 4096,
};
enum : size_t {   // ushort-index offsets inside bf16 region
  BF_CHH0 = 0,
  BF_CIH1 = BF_CHH0 + (size_t)2048 * 512,
  BF_CHH1 = BF_CIH1 + (size_t)2048 * 512,
  BF_C2E  = BF_CHH1 + (size_t)2048 * 512,
  BF_WIH0 = BF_C2E  + (size_t)1024 * 512,
  BF_WHH0 = BF_WIH0 + (size_t)4096 * 1024,
  BF_WIH1 = BF_WHH0 + (size_t)4096 * 1024,
  BF_WHH1 = BF_WIH1 + (size_t)4096 * 1024,
};

// ---------------- small helpers ----------------
__device__ __forceinline__ float bf2f(unsigned short b) {
  return __uint_as_float(((unsigned)b) << 16);
}
__device__ __forceinline__ unsigned short f2bf(float x) {   // RNE
  unsigned u = __float_as_uint(x);
  u += 0x7FFFu + ((u >> 16) & 1u);
  return (unsigned short)(u >> 16);
}
__device__ __forceinline__ float wred(float v) {
  #pragma unroll
  for (int off = 32; off > 0; off >>= 1) v += __shfl_xor(v, off, 64);
  return v;
}
__device__ __forceinline__ float sigm(float x) { return 1.f / (1.f + __expf(-x)); }
__device__ __forceinline__ float tanh_(float x) {
  float a = fabsf(x);
  float e = __expf(-2.f * a);
  float t = (1.f - e) / (1.f + e);
  return copysignf(t, x);
}
__device__ __forceinline__ float lstm_cell(float zi, float zf, float zg, float zo, float& c) {
  float i = sigm(zi), f = sigm(zf), g = tanh_(zg), o = sigm(zo);
  c = f * c + i * g;
  return o * tanh_(c);
}
__device__ __forceinline__ i4v pk2(float a, float b, int tag) {
  i4v v; v.x = __float_as_int(a); v.y = tag; v.z = __float_as_int(b); v.w = tag;
  return v;
}

// ---- tagged-pair primitives (sc0 sc1 = MALL-coherent bypass everywhere) ----
__device__ __forceinline__ void st16(int* p, i4v v) {
  asm volatile("global_store_dwordx4 %0, %1, off sc0 sc1" :: "v"(p), "v"(v) : "memory");
}
__device__ __forceinline__ void st8(int* p, float val, int tag) {
  i2v v; v.x = __float_as_int(val); v.y = tag;
  asm volatile("global_store_dwordx2 %0, %1, off sc0 sc1" :: "v"(p), "v"(v) : "memory");
}
__device__ __forceinline__ float pollpair(const int* p, int tag) {
  for (;;) {
    i2v v;
    asm volatile("global_load_dwordx2 %0, %1, off sc0 sc1\n\ts_waitcnt vmcnt(0)"
                 : "=v"(v) : "v"(p) : "memory");
    if (v.y == tag) return __int_as_float(v.x);
    __builtin_amdgcn_s_sleep(16);
  }
}
// probe 4 pairs (32B): char hot path
template<int SLP>
__device__ __forceinline__ void probe32x(const int* p, int tag, float* out) {
  i4v a, b;
  for (;;) {
    asm volatile(
        "global_load_dwordx4 %0, %2, off sc0 sc1\n\t"
        "global_load_dwordx4 %1, %2, off offset:16 sc0 sc1\n\t"
        "s_waitcnt vmcnt(0)"
        : "=&v"(a), "=&v"(b) : "v"(p) : "memory");
    int ok = (a.y == tag) & (a.w == tag) & (b.y == tag) & (b.w == tag);
    if (__all(ok)) break;
    if constexpr (SLP > 0) __builtin_amdgcn_s_sleep(SLP);
  }
  out[0] = __int_as_float(a.x); out[1] = __int_as_float(a.z);
  out[2] = __int_as_float(b.x); out[3] = __int_as_float(b.z);
}
// probe 2 pairs (16B)
template<int SLP>
__device__ __forceinline__ void probe2(const int* p, int tag, float* out) {
  i4v a;
  for (;;) {
    asm volatile("global_load_dwordx4 %0, %1, off sc0 sc1\n\ts_waitcnt vmcnt(0)"
                 : "=&v"(a) : "v"(p) : "memory");
    int ok = (a.y == tag) & (a.w == tag);
    if (__all(ok)) break;
    if constexpr (SLP > 0) __builtin_amdgcn_s_sleep(SLP);
  }
  out[0] = __int_as_float(a.x); out[1] = __int_as_float(a.z);
}

__device__ __forceinline__ void load8(const float* p, int lane, float* h) {
  const f4* q = (const f4*)(p + (lane << 3));
  f4 a = q[0], b = q[1];
  h[0]=a.x; h[1]=a.y; h[2]=a.z; h[3]=a.w;
  h[4]=b.x; h[5]=b.y; h[6]=b.z; h[7]=b.w;
}
__device__ __forceinline__ float rowdot512(const unsigned short* __restrict__ W, int r,
                                           const float* h8, int lane) {
  us8 w = *(const us8*)(W + ((size_t)r << 9) + (lane << 3));
  float s = 0.f;
  #pragma unroll
  for (int u = 0; u < 8; u++) s += bf2f(w[u]) * h8[u];
  return s;
}
__device__ __forceinline__ float rowdot1024(const unsigned short* __restrict__ W, int r,
                                            const float* h16, int lane) {
  const unsigned short* p = W + ((size_t)r << 10) + (lane << 4);
  us8 w0 = *(const us8*)p;
  us8 w1 = *(const us8*)(p + 8);
  float s = 0.f;
  #pragma unroll
  for (int u = 0; u < 8; u++) s += bf2f(w0[u]) * h16[u];
  #pragma unroll
  for (int u = 0; u < 8; u++) s += bf2f(w1[u]) * h16[8 + u];
  return s;
}

// ---------------- prep kernels (unchanged) ----------------
__global__ void k_convert(const float* __restrict__ src, unsigned short* __restrict__ dst, int n) {
  int i = blockIdx.x * blockDim.x + threadIdx.x;
  int stride = gridDim.x * blockDim.x;
  for (; i < n; i += stride) dst[i] = f2bf(src[i]);
}
__global__ void k_bias(const float* __restrict__ cbih, const float* __restrict__ cbhh,
                       const float* __restrict__ wbih, const float* __restrict__ wbhh,
                       float* __restrict__ b1, float* __restrict__ bw0, float* __restrict__ bw1) {
  int i = blockIdx.x * blockDim.x + threadIdx.x;
  if (i < 2048) b1[i] = cbih[2048 + i] + cbhh[2048 + i];
  if (i < 4096) {
    bw0[i] = wbih[i] + wbhh[i];
    bw1[i] = wbih[4096 + i] + wbhh[4096 + i];
  }
}
__global__ void k_pre0(const float* __restrict__ Wih0, const float* __restrict__ emb,
                       const float* __restrict__ bih0, const float* __restrict__ bhh0,
                       float* __restrict__ pre0) {
  int wid  = (blockIdx.x * blockDim.x + threadIdx.x) >> 6;
  int lane = threadIdx.x & 63;
  int nw   = (gridDim.x * blockDim.x) >> 6;
  for (int row = wid; row < VCHAR * 2048; row += nw) {
    int c = row >> 11, r = row & 2047;
    float e8[8];
    load8(emb + ((size_t)c << 9), lane, e8);
    const f4* wp = (const f4*)(Wih0 + ((size_t)r << 9) + (lane << 3));
    f4 a = wp[0], b = wp[1];
    float s = a.x*e8[0] + a.y*e8[1] + a.z*e8[2] + a.w*e8[3]
            + b.x*e8[4] + b.y*e8[5] + b.z*e8[6] + b.w*e8[7];
    s = wred(s);
    if (lane == 0) pre0[row] = s + bih0[r] + bhh0[r];
  }
}
__global__ void k_xwg(const int* __restrict__ xwords, const float* __restrict__ glove,
                      const float* __restrict__ gw, const float* __restrict__ gb,
                      float* __restrict__ xw, float* __restrict__ g) {
  __shared__ float red[4];
  int t = blockIdx.x, tid = threadIdx.x;
  const float* row = glove + (size_t)xwords[t] * HWD;
  f4 v = ((const f4*)row)[tid];
  ((f4*)(xw + (size_t)t * HWD))[tid] = v;
  f4 w = ((const f4*)gw)[tid];
  float s = v.x*w.x + v.y*w.y + v.z*w.z + v.w*w.w;
  s = wred(s);
  if ((tid & 63) == 0) red[tid >> 6] = s;
  __syncthreads();
  if (tid == 0) {
    float tot = red[0] + red[1] + red[2] + red[3] + gb[0];
    g[t] = tot > 0.f ? tot : 0.f;
  }
}

// ---------------- the persistent sequential kernel ----------------
struct SeqP {
  const int* x_chars;
  const float* h_char0; const float* c_char0;
  const float* h_word0; const float* c_word0;
  int *pub2, *hw02, *hw12, *c1h;
  float* y;
  const float *gt, *xw, *pre0, *b1, *bw0, *bw1;
  const unsigned short *Whh0, *Wih1, *Whh1, *c2e;
  const unsigned short *wWih0, *wWhh0, *wWih1, *wWhh1;
  float* out;
};

__global__ __launch_bounds__(NTHR) void k_seq(SeqP P) {
  // char uses lds[0..1023]; word: c1[0..511] xg[512..1535] a[1536..2559] b[2560..3583] c[3584..4607]
  __shared__ float lds[4608];

  const int tid  = threadIdx.x;
  const int lane = tid & 63;
  const int wv   = tid >> 6;
  const int bid  = blockIdx.x;

  const size_t LOG = (size_t)T_STEPS * VWORD;
  float* o_hw = P.out + LOG;
  float* o_cw = o_hw + 2048;
  float* o_hc = o_cw + 2048;
  float* o_cc = o_hc + 1024;

  // ================= CHAR CLUSTER (bid 0..15): 16 WGs, MALL seqlock =================
  if (bid < 16) {
    const int k   = bid;
    const int j0w = k * 32 + wv * 8;     // wave owns 8 rows of each char layer

    // init tagged pairs: pub slot1 full (tag -1), pub slot0 h1-part (tag 0).
    {
      int g = k * 256 + tid;             // 0..4095
      if (g < 1024) st8(P.pub2 + 2048 + g * 2, P.h_char0[g], -1);
      else if (g < 1536) {
        int e = 512 + (g - 1024);
        st8(P.pub2 + e * 2, P.h_char0[e], 0);
      }
    }

    float c0s[8], c1s[8], fh0[8], fh1[8];
    #pragma unroll
    for (int jj = 0; jj < 8; jj++) {
      c0s[jj] = P.c_char0[j0w + jj];
      c1s[jj] = P.c_char0[512 + j0w + jj];
      fh0[jj] = 0.f; fh1[jj] = 0.f;
    }

    for (int r = 0; r <= 4096; r++) {
      const int rp = (r - 1) & 1, wp = r & 1;
      // ---- probe: wave wv covers pair quarter [wv*256, wv*256+256), 4 pairs/lane ----
      {
        int lane2 = (lane + k) & 63;
        int pairidx = wv * 256 + lane2 * 4;
        float v[4];
        probe32x<0>(P.pub2 + (rp * 1024 + pairidx) * 2, r - 1, v);
        f4 fv; fv.x = v[0]; fv.y = v[1]; fv.z = v[2]; fv.w = v[3];
        *(f4*)&lds[pairidx] = fv;
      }
      __syncthreads();

      float h8[8], b8[8];
      load8(lds, lane, h8);
      load8(lds + 512, lane, b8);

      float hv0[8], hv1[8];
      const bool do_l0 = (r < 4096), do_l1 = (r >= 1);

      if (do_l0) {   // char layer 0 for cs = r
        const int ci = P.x_chars[r];
        const float* preb = P.pre0 + (size_t)ci * 2048;
        #pragma unroll
        for (int jj = 0; jj < 8; jj++) {
          int j = j0w + jj;
          float zi = wred(rowdot512(P.Whh0,        j, h8, lane)) + preb[j];
          float zf = wred(rowdot512(P.Whh0,  512 + j, h8, lane)) + preb[512 + j];
          float zg = wred(rowdot512(P.Whh0, 1024 + j, h8, lane)) + preb[1024 + j];
          float zo = wred(rowdot512(P.Whh0, 1536 + j, h8, lane)) + preb[1536 + j];
          hv0[jj] = lstm_cell(zi, zf, zg, zo, c0s[jj]);
          if (r == 4095) fh0[jj] = hv0[jj];
        }
      }
      if (do_l1) {   // char layer 1 for cs = r-1 (input h0(cs=r-1) == h8)
        #pragma unroll
        for (int jj = 0; jj < 8; jj++) {
          int j = j0w + jj;
          float z[4];
          #pragma unroll
          for (int gq = 0; gq < 4; gq++) {
            int rr = gq * 512 + j;
            z[gq] = wred(rowdot512(P.Wih1, rr, h8, lane)
                       + rowdot512(P.Whh1, rr, b8, lane)) + P.b1[rr];
          }
          hv1[jj] = lstm_cell(z[0], z[1], z[2], z[3], c1s[jj]);
          if (r == 4096) fh1[jj] = hv1[jj];
        }
      }

      // ---- publish (lanes 0..3, one st16 = 2 pairs each; values wave-uniform) ----
      if (do_l0 && lane < 4) {
        st16(P.pub2 + (wp * 1024 + j0w + lane * 2) * 2,
             pk2(hv0[lane * 2], hv0[lane * 2 + 1], r));
      }
      if (do_l1 && lane < 4) {
        st16(P.pub2 + (wp * 1024 + 512 + j0w + lane * 2) * 2,
             pk2(hv1[lane * 2], hv1[lane * 2 + 1], r));
        if (((r - 1) & 15) == 15) {      // c1 snapshot -> append-only history
          int t = (r - 1) >> 4;
          st16(P.c1h + ((size_t)t * 512 + j0w + lane * 2) * 2,
               pk2(c1s[lane * 2], c1s[lane * 2 + 1], t));
        }
      }
      __syncthreads();
    }

    // ---- char epilogue (own rows, from registers) ----
    if (lane == 0) {
      #pragma unroll
      for (int jj = 0; jj < 8; jj++) {
        o_cc[j0w + jj]       = c0s[jj];
        o_cc[512 + j0w + jj] = c1s[jj];
        o_hc[j0w + jj]       = fh0[jj];
        o_hc[512 + j0w + jj] = fh1[jj];
      }
    }
    return;
  }

  // ================= WORD CLUSTER (bid 16..79): 64 WGs, MALL seqlock =================
  {
    const int w   = bid - 16;                      // 0..63
    const int m0w = w * 16 + wv * 4;               // wave owns 4 rows per word layer

    float cw0s[4], cw1s[4];
    #pragma unroll
    for (int mm = 0; mm < 4; mm++) {
      cw0s[mm] = P.c_word0[m0w + mm];
      cw1s[mm] = P.c_word0[1024 + m0w + mm];
    }

    if (bid == 16) {       // init hw0 slot1 (tag -1)
      for (int g = tid; g < 1024; g += NTHR) st8(P.hw02 + (1024 + g) * 2, P.h_word0[g], -1);
    } else if (bid == 17) { // init hw1 slot1 (tag -1)
      for (int g = tid; g < 1024; g += NTHR) st8(P.hw12 + (1024 + g) * 2, P.h_word0[1024 + g], -1);
    }

    float* lc1 = lds;
    float* lxg = lds + 512;
    float* la  = lds + 1536;
    float* lb  = lds + 2560;
    float* lcc = lds + 3584;

    float fw0[4], fw1[4];
    #pragma unroll
    for (int mm = 0; mm < 4; mm++) { fw0[mm] = 0.f; fw1[mm] = 0.f; }

    for (int t = 0; t < T_STEPS; t++) {
      const int os = (t & 1) ^ 1, ns = t & 1;
      // ---- stage 1: probe c1(t) history, hw0old(t-1), hw1old(t-1) ----
      {
        int chunk = wv * 64 + ((lane + w) & 63);   // 0..255
        { float v[2];
          probe2<8>(P.c1h + ((size_t)t * 512 + chunk * 2) * 2, t, v);
          lc1[chunk * 2] = v[0]; lc1[chunk * 2 + 1] = v[1]; }
        { float v[4];
          probe32x<1>(P.hw02 + (os * 1024 + chunk * 4) * 2, t - 1, v);
          f4 fv; fv.x=v[0]; fv.y=v[1]; fv.z=v[2]; fv.w=v[3];
          *(f4*)&lb[chunk * 4] = fv; }
        { float v[4];
          probe32x<1>(P.hw12 + (os * 1024 + chunk * 4) * 2, t - 1, v);
          f4 fv; fv.x=v[0]; fv.y=v[1]; fv.z=v[2]; fv.w=v[3];
          *(f4*)&lcc[chunk * 4] = fv; }
      }
      __syncthreads();

      // ---- stage 2: redundant gate -> lxg (each wave computes 256 rows) ----
      {
        float cg8[8];
        load8(lc1, lane, cg8);
        const float gv = P.gt[t];
        const float* xwrow = P.xw + (size_t)t * HWD;
        #pragma unroll 4
        for (int i = 0; i < 256; i++) {
          int m = wv * 256 + i;
          float xc = wred(rowdot512(P.c2e, m, cg8, lane));
          if (lane == 0) lxg[m] = (1.f - gv) * xwrow[m] + gv * xc;
        }
      }
      __syncthreads();

      // ---- stage 3: word layer 0 ----
      float hv0[4];
      {
        float x16[16], h16[16];
        const f4* pa = (const f4*)&lxg[lane << 4];
        const f4* pb = (const f4*)&lb[lane << 4];
        #pragma unroll
        for (int kk = 0; kk < 4; kk++) {
          f4 va = pa[kk], vb = pb[kk];
          x16[4*kk+0]=va.x; x16[4*kk+1]=va.y; x16[4*kk+2]=va.z; x16[4*kk+3]=va.w;
          h16[4*kk+0]=vb.x; h16[4*kk+1]=vb.y; h16[4*kk+2]=vb.z; h16[4*kk+3]=vb.w;
        }
        #pragma unroll
        for (int mm = 0; mm < 4; mm++) {
          int m = m0w + mm;
          float z[4];
          #pragma unroll
          for (int gq = 0; gq < 4; gq++) {
            int rr = (gq << 10) + m;
            z[gq] = wred(rowdot1024(P.wWih0, rr, x16, lane)
                       + rowdot1024(P.wWhh0, rr, h16, lane)) + P.bw0[rr];
          }
          hv0[mm] = lstm_cell(z[0], z[1], z[2], z[3], cw0s[mm]);
        }
      }
      if (lane < 2)
        st16(P.hw02 + (ns * 1024 + m0w + lane * 2) * 2,
             pk2(hv0[lane * 2], hv0[lane * 2 + 1], t));

      // ---- probe hw0new(t) -> la ----
      {
        int chunk = wv * 64 + ((lane + w) & 63);
        float v[4];
        probe32x<1>(P.hw02 + (ns * 1024 + chunk * 4) * 2, t, v);
        f4 fv; fv.x=v[0]; fv.y=v[1]; fv.z=v[2]; fv.w=v[3];
        *(f4*)&la[chunk * 4] = fv;
      }
      __syncthreads();

      // ---- stage 4: word layer 1 (top output -> y[t]) ----
      float hv1[4];
      {
        float a16[16], b16[16];
        const f4* pa = (const f4*)&la[lane << 4];
        const f4* pb = (const f4*)&lcc[lane << 4];
        #pragma unroll
        for (int kk = 0; kk < 4; kk++) {
          f4 va = pa[kk], vb = pb[kk];
          a16[4*kk+0]=va.x; a16[4*kk+1]=va.y; a16[4*kk+2]=va.z; a16[4*kk+3]=va.w;
          b16[4*kk+0]=vb.x; b16[4*kk+1]=vb.y; b16[4*kk+2]=vb.z; b16[4*kk+3]=vb.w;
        }
        #pragma unroll
        for (int mm = 0; mm < 4; mm++) {
          int m = m0w + mm;
          float z[4];
          #pragma unroll
          for (int gq = 0; gq < 4; gq++) {
            int rr = (gq << 10) + m;
            z[gq] = wred(rowdot1024(P.wWih1, rr, a16, lane)
                       + rowdot1024(P.wWhh1, rr, b16, lane)) + P.bw1[rr];
          }
          hv1[mm] = lstm_cell(z[0], z[1], z[2], z[3], cw1s[mm]);
        }
      }
      if (lane < 2)
        st16(P.hw12 + (ns * 1024 + m0w + lane * 2) * 2,
             pk2(hv1[lane * 2], hv1[lane * 2 + 1], t));
      if (lane == 0) {
        float* yrow = P.y + (size_t)t * HWD;
        yrow[m0w]     = hv1[0];
        yrow[m0w + 1] = hv1[1];
        yrow[m0w + 2] = hv1[2];
        yrow[m0w + 3] = hv1[3];
      }
      if (t == T_STEPS - 1) {
        #pragma unroll
        for (int mm = 0; mm < 4; mm++) { fw0[mm] = hv0[mm]; fw1[mm] = hv1[mm]; }
      }
      __syncthreads();
    }

    // ---- word epilogue (own rows, from registers) ----
    if (lane == 0) {
      #pragma unroll
      for (int mm = 0; mm < 4; mm++) {
        o_hw[m0w + mm]        = fw0[mm];
        o_hw[1024 + m0w + mm] = fw1[mm];
        o_cw[m0w + mm]        = cw0s[mm];
        o_cw[1024 + m0w + mm] = cw1s[mm];
      }
    }
  }
}

// ---------------- decoder GEMM (unchanged) ----------------
__global__ __launch_bounds__(256) void k_decoder(const float* __restrict__ y,
                                                 const float* __restrict__ W,
                                                 const float* __restrict__ bias,
                                                 float* __restrict__ out) {
  __shared__ float As[32][65];
  __shared__ float Bs[32][65];
  const int tid = threadIdx.x;
  const int v0 = blockIdx.x * 64;
  const int t0 = blockIdx.y * 64;
  const int tx = tid & 15, ty = tid >> 4;
  float acc[4][4] = {};
  for (int k0 = 0; k0 < 1024; k0 += 32) {
    #pragma unroll
    for (int e = 0; e < 2; e++) {
      int fi = tid * 2 + e;
      int rr = fi >> 3;
      int kk = (fi & 7) << 2;
      f4 av = *(const f4*)(y + (size_t)(t0 + rr) * 1024 + k0 + kk);
      As[kk][rr] = av.x; As[kk+1][rr] = av.y; As[kk+2][rr] = av.z; As[kk+3][rr] = av.w;
      int vg = v0 + rr;
      f4 bv;
      if (vg < VWORD) bv = *(const f4*)(W + (size_t)vg * 1024 + k0 + kk);
      else { bv.x = 0.f; bv.y = 0.f; bv.z = 0.f; bv.w = 0.f; }
      Bs[kk][rr] = bv.x; Bs[kk+1][rr] = bv.y; Bs[kk+2][rr] = bv.z; Bs[kk+3][rr] = bv.w;
    }
    __syncthreads();
    #pragma unroll
    for (int kk = 0; kk < 32; kk++) {
      float a[4], b[4];
      #pragma unroll
      for (int i = 0; i < 4; i++) a[i] = As[kk][ty * 4 + i];
      #pragma unroll
      for (int j = 0; j < 4; j++) b[j] = Bs[kk][tx * 4 + j];
      #pragma unroll
      for (int i = 0; i < 4; i++)
        #pragma unroll
        for (int j = 0; j < 4; j++) acc[i][j] += a[i] * b[j];
    }
    __syncthreads();
  }
  #pragma unroll
  for (int i = 0; i < 4; i++) {
    int t = t0 + ty * 4 + i;
    #pragma unroll
    for (int j = 0; j < 4; j++) {
      int v = v0 + tx * 4 + j;
      if (v < VWORD) out[(size_t)t * VWORD + v] = acc[i][j] + bias[v];
    }
  }
}

// ---------------- host launch ----------------
extern "C" void kernel_launch(void* const* d_in, const int* in_sizes, int n_in,
                              void* d_out, int out_size, void* d_ws, size_t ws_size,
                              hipStream_t stream) {
  const int*   x_words  = (const int*)d_in[0];
  const int*   x_chars  = (const int*)d_in[1];
  const float* h_word0  = (const float*)d_in[2];
  const float* c_word0  = (const float*)d_in[3];
  const float* h_char0  = (const float*)d_in[4];
  const float* c_char0  = (const float*)d_in[5];
  const float* glove    = (const float*)d_in[6];
  const float* char_emb = (const float*)d_in[7];
  const float* char_Wih = (const float*)d_in[8];
  const float* char_Whh = (const float*)d_in[9];
  const float* char_bih = (const float*)d_in[10];
  const float* char_bhh = (const float*)d_in[11];
  const float* word_Wih = (const float*)d_in[12];
  const float* word_Whh = (const float*)d_in[13];
  const float* word_bih = (const float*)d_in[14];
  const float* word_bhh = (const float*)d_in[15];
  const float* c2e      = (const float*)d_in[16];
  const float* g_w      = (const float*)d_in[17];
  const float* g_b      = (const float*)d_in[18];
  const float* dec_W    = (const float*)d_in[19];
  const float* dec_b    = (const float*)d_in[20];

  float* out = (float*)d_out;
  float* ws  = (float*)d_ws;
  int*   wsi = (int*)d_ws;
  unsigned short* bfb = (unsigned short*)(ws + WS_BF);

  // reset all exchange tags (0xAAAAAAAA never equals a valid tag)
  hipMemsetAsync(wsi, 0xAA, I_END * sizeof(int), stream);

  k_convert<<<1024, 256, 0, stream>>>(char_Whh,                       bfb + BF_CHH0, 2048 * 512);
  k_convert<<<1024, 256, 0, stream>>>(char_Wih + (size_t)2048 * 512,  bfb + BF_CIH1, 2048 * 512);
  k_convert<<<1024, 256, 0, stream>>>(char_Whh + (size_t)2048 * 512,  bfb + BF_CHH1, 2048 * 512);
  k_convert<<<1024, 256, 0, stream>>>(c2e,                            bfb + BF_C2E,  1024 * 512);
  k_convert<<<2048, 256, 0, stream>>>(word_Wih,                       bfb + BF_WIH0, 4096 * 1024);
  k_convert<<<2048, 256, 0, stream>>>(word_Whh,                       bfb + BF_WHH0, 4096 * 1024);
  k_convert<<<2048, 256, 0, stream>>>(word_Wih + (size_t)4096 * 1024, bfb + BF_WIH1, 4096 * 1024);
  k_convert<<<2048, 256, 0, stream>>>(word_Whh + (size_t)4096 * 1024, bfb + BF_WHH1, 4096 * 1024);
  k_bias<<<16, 256, 0, stream>>>(char_bih, char_bhh, word_bih, word_bhh,
                                 ws + WS_B1, ws + WS_BW0, ws + WS_BW1);
  k_pre0<<<256, 256, 0, stream>>>(char_Wih, char_emb, char_bih, char_bhh, ws + WS_PRE0);
  k_xwg<<<256, 256, 0, stream>>>(x_words, glove, g_w, g_b, ws + WS_XW, ws + WS_G);

  SeqP P;
  P.x_chars = x_chars;
  P.h_char0 = h_char0;  P.c_char0 = c_char0;
  P.h_word0 = h_word0;  P.c_word0 = c_word0;
  P.pub2 = wsi + I_PUB;  P.hw02 = wsi + I_HW0;  P.hw12 = wsi + I_HW1;
  P.c1h  = wsi + I_C1H;
  P.y   = ws + WS_Y;
  P.gt  = ws + WS_G;    P.xw  = ws + WS_XW;   P.pre0 = ws + WS_PRE0;
  P.b1  = ws + WS_B1;   P.bw0 = ws + WS_BW0;  P.bw1 = ws + WS_BW1;
  P.Whh0 = bfb + BF_CHH0;  P.Wih1 = bfb + BF_CIH1;  P.Whh1 = bfb + BF_CHH1;
  P.c2e  = bfb + BF_C2E;
  P.wWih0 = bfb + BF_WIH0;  P.wWhh0 = bfb + BF_WHH0;
  P.wWih1 = bfb + BF_WIH1;  P.wWhh1 = bfb + BF_WHH1;
  P.out = out;

  k_seq<<<NWG, NTHR, 0, stream>>>(P);

  k_decoder<<<dim3((VWORD + 63) / 64, 4), 256, 0, stream>>>(ws + WS_Y, dec_W, dec_b, out);
}

// Round 16
// 42691.068 us; speedup vs baseline: 2.0929x; 2.0929x over previous
//
#include <hip/hip_runtime.h>
#include <hip/hip_bf16.h>
#include <stdint.h>
#include <stddef.h>

// ---------------- problem constants ----------------
#define T_STEPS 256
#define CLEN    16
#define HWD     1024
#define HCD     512
#define VWORD   50257
#define VCHAR   62

// ---------------- seq-kernel config ----------------
#define NWG   64
#define NTHR  256     // 4 waves/WG; 64 blocks <= 256 CUs => always co-resident
#define NROUNDS 4100  // l0 @ r, l1 @ r-1, gate/wl0/wl1 @ 16t+17/18/19
#define RDEPTH 64     // char pub ring depth

typedef __attribute__((ext_vector_type(4))) float f4;
typedef __attribute__((ext_vector_type(8))) unsigned short us8;
typedef __attribute__((ext_vector_type(4))) int i4v;
typedef __attribute__((ext_vector_type(2))) int i2v;

// ---------------- workspace layout ----------------
// Char h0/h1 exchange through a 64-slot RING of (value,tag) pair records —
// a line is rewritten every 64 rounds (~650us) instead of every 2, amortizing
// any coherence-ownership teardown on the store path.
// RING(r) = ring2 + (r & 63)*2048 ints (1024 pairs: h0[512], h1[512]), tag r.
// Pair p of slot s lives at int offset s*2048 + p*2.
enum : size_t {
  I_RING = 0,                        // ring2[64][1024][2] = 131072 ints
  I_C1C  = (size_t)RDEPTH * 2048,    // c1c2[512][2]
  I_XG   = I_C1C + 1024,             // xg2[1024][2]
  I_HW0  = I_XG + 2048,              // hw02[2][1024][2]
  I_HW1  = I_HW0 + 4096,             // hw12[2][1024][2]
  I_END  = I_HW1 + 4096,             // ints; memset 0xAA per launch (~570KB)
};
// float-indexed region (same 4B index space, after the pairs):
enum : size_t {
  WS_G    = I_END,                          // g[256]
  WS_XW   = WS_G + 256,                     // xw[256][1024]
  WS_Y    = WS_XW + (size_t)T_STEPS * HWD,  // y[256][1024]
  WS_PRE0 = WS_Y + (size_t)T_STEPS * HWD,   // pre0[62][2048]
  WS_B1   = WS_PRE0 + (size_t)VCHAR * 2048,
  WS_BW0  = WS_B1 + 2048,
  WS_BW1  = WS_BW0 + 4096,
  WS_BF   = WS_BW1 + 4096,                  // start of bf16 (ushort) region
};
enum : size_t {   // ushort-index offsets inside bf16 region
  BF_CHH0 = 0,
  BF_CIH1 = BF_CHH0 + (size_t)2048 * 512,
  BF_CHH1 = BF_CIH1 + (size_t)2048 * 512,
  BF_C2E  = BF_CHH1 + (size_t)2048 * 512,
  BF_WIH0 = BF_C2E  + (size_t)1024 * 512,
  BF_WHH0 = BF_WIH0 + (size_t)4096 * 1024,
  BF_WIH1 = BF_WHH0 + (size_t)4096 * 1024,
  BF_WHH1 = BF_WIH1 + (size_t)4096 * 1024,
};

// ---------------- small helpers ----------------
__device__ __forceinline__ float bf2f(unsigned short b) {
  return __uint_as_float(((unsigned)b) << 16);
}
__device__ __forceinline__ unsigned short f2bf(float x) {   // RNE
  unsigned u = __float_as_uint(x);
  u += 0x7FFFu + ((u >> 16) & 1u);
  return (unsigned short)(u >> 16);
}
__device__ __forceinline__ float wred(float v) {
  #pragma unroll
  for (int off = 32; off > 0; off >>= 1) v += __shfl_xor(v, off, 64);
  return v;
}
__device__ __forceinline__ float sigm(float x) { return 1.f / (1.f + __expf(-x)); }
__device__ __forceinline__ float tanh_(float x) {
  float a = fabsf(x);
  float e = __expf(-2.f * a);
  float t = (1.f - e) / (1.f + e);
  return copysignf(t, x);
}
__device__ __forceinline__ float lstm_cell(float zi, float zf, float zg, float zo, float& c) {
  float i = sigm(zi), f = sigm(zf), g = tanh_(zg), o = sigm(zo);
  c = f * c + i * g;
  return o * tanh_(c);
}

// ---- tagged-pair primitives (sc0 sc1 = coherent bypass, served at MALL) ----
__device__ __forceinline__ i4v pk2(float a, float b, int tag) {
  i4v v; v.x = __float_as_int(a); v.y = tag; v.z = __float_as_int(b); v.w = tag;
  return v;
}
__device__ __forceinline__ void st16(int* p, i4v v) {
  asm volatile("global_store_dwordx4 %0, %1, off sc0 sc1" :: "v"(p), "v"(v) : "memory");
}
__device__ __forceinline__ void st8(int* p, float val, int tag) {
  i2v v; v.x = __float_as_int(val); v.y = tag;
  asm volatile("global_store_dwordx2 %0, %1, off sc0 sc1" :: "v"(p), "v"(v) : "memory");
}
__device__ __forceinline__ float pollpair(const int* p, int tag) {
  for (;;) {
    i2v v;
    asm volatile("global_load_dwordx2 %0, %1, off sc0 sc1\n\ts_waitcnt vmcnt(0)"
                 : "=v"(v) : "v"(p) : "memory");
    if (v.y == tag) return __int_as_float(v.x);
    __builtin_amdgcn_s_sleep(16);
  }
}
// poll a 512-elem pair region: lane covers 8 elems (chunk c), returns values.
__device__ __forceinline__ void probe512(const int* base, int c, int tag, float* out) {
  const int* p = base + (c << 4);          // 16 ints = 8 pairs per chunk
  i4v b0, b1, b2, b3;
  for (;;) {
    asm volatile(
        "global_load_dwordx4 %0, %4, off sc0 sc1\n\t"
        "global_load_dwordx4 %1, %4, off offset:16 sc0 sc1\n\t"
        "global_load_dwordx4 %2, %4, off offset:32 sc0 sc1\n\t"
        "global_load_dwordx4 %3, %4, off offset:48 sc0 sc1\n\t"
        "s_waitcnt vmcnt(0)"
        : "=&v"(b0), "=&v"(b1), "=&v"(b2), "=&v"(b3)
        : "v"(p) : "memory");
    int ok = (b0.y==tag) & (b0.w==tag) & (b1.y==tag) & (b1.w==tag)
           & (b2.y==tag) & (b2.w==tag) & (b3.y==tag) & (b3.w==tag);
    if (__all(ok)) break;
  }
  out[0]=__int_as_float(b0.x); out[1]=__int_as_float(b0.z);
  out[2]=__int_as_float(b1.x); out[3]=__int_as_float(b1.z);
  out[4]=__int_as_float(b2.x); out[5]=__int_as_float(b2.z);
  out[6]=__int_as_float(b3.x); out[7]=__int_as_float(b3.z);
}
// poll a 1024-elem pair region: lane covers 16 elems (chunk c)
__device__ __forceinline__ void probe1024(const int* base, int c, int tag, float* out) {
  const int* p = base + (c << 5);          // 32 ints = 16 pairs per chunk
  i4v b0,b1,b2,b3,b4,b5,b6,b7;
  for (;;) {
    asm volatile(
        "global_load_dwordx4 %0, %8, off sc0 sc1\n\t"
        "global_load_dwordx4 %1, %8, off offset:16 sc0 sc1\n\t"
        "global_load_dwordx4 %2, %8, off offset:32 sc0 sc1\n\t"
        "global_load_dwordx4 %3, %8, off offset:48 sc0 sc1\n\t"
        "global_load_dwordx4 %4, %8, off offset:64 sc0 sc1\n\t"
        "global_load_dwordx4 %5, %8, off offset:80 sc0 sc1\n\t"
        "global_load_dwordx4 %6, %8, off offset:96 sc0 sc1\n\t"
        "global_load_dwordx4 %7, %8, off offset:112 sc0 sc1\n\t"
        "s_waitcnt vmcnt(0)"
        : "=&v"(b0),"=&v"(b1),"=&v"(b2),"=&v"(b3),
          "=&v"(b4),"=&v"(b5),"=&v"(b6),"=&v"(b7)
        : "v"(p) : "memory");
    int ok = (b0.y==tag)&(b0.w==tag)&(b1.y==tag)&(b1.w==tag)
           & (b2.y==tag)&(b2.w==tag)&(b3.y==tag)&(b3.w==tag)
           & (b4.y==tag)&(b4.w==tag)&(b5.y==tag)&(b5.w==tag)
           & (b6.y==tag)&(b6.w==tag)&(b7.y==tag)&(b7.w==tag);
    if (__all(ok)) break;
  }
  out[0] =__int_as_float(b0.x); out[1] =__int_as_float(b0.z);
  out[2] =__int_as_float(b1.x); out[3] =__int_as_float(b1.z);
  out[4] =__int_as_float(b2.x); out[5] =__int_as_float(b2.z);
  out[6] =__int_as_float(b3.x); out[7] =__int_as_float(b3.z);
  out[8] =__int_as_float(b4.x); out[9] =__int_as_float(b4.z);
  out[10]=__int_as_float(b5.x); out[11]=__int_as_float(b5.z);
  out[12]=__int_as_float(b6.x); out[13]=__int_as_float(b6.z);
  out[14]=__int_as_float(b7.x); out[15]=__int_as_float(b7.z);
}

__device__ __forceinline__ void load8(const float* p, int lane, float* h) {
  const f4* q = (const f4*)(p + (lane << 3));
  f4 a = q[0], b = q[1];
  h[0]=a.x; h[1]=a.y; h[2]=a.z; h[3]=a.w;
  h[4]=b.x; h[5]=b.y; h[6]=b.z; h[7]=b.w;
}
__device__ __forceinline__ float rowdot512(const unsigned short* __restrict__ W, int r,
                                           const float* h8, int lane) {
  us8 w = *(const us8*)(W + ((size_t)r << 9) + (lane << 3));
  float s = 0.f;
  #pragma unroll
  for (int u = 0; u < 8; u++) s += bf2f(w[u]) * h8[u];
  return s;
}
__device__ __forceinline__ float rowdot1024(const unsigned short* __restrict__ W, int r,
                                            const float* h16, int lane) {
  const unsigned short* p = W + ((size_t)r << 10) + (lane << 4);
  us8 w0 = *(const us8*)p;
  us8 w1 = *(const us8*)(p + 8);
  float s = 0.f;
  #pragma unroll
  for (int u = 0; u < 8; u++) s += bf2f(w0[u]) * h16[u];
  #pragma unroll
  for (int u = 0; u < 8; u++) s += bf2f(w1[u]) * h16[8 + u];
  return s;
}

// ---------------- prep kernels ----------------
__global__ void k_convert(const float* __restrict__ src, unsigned short* __restrict__ dst, int n) {
  int i = blockIdx.x * blockDim.x + threadIdx.x;
  int stride = gridDim.x * blockDim.x;
  for (; i < n; i += stride) dst[i] = f2bf(src[i]);
}

__global__ void k_bias(const float* __restrict__ cbih, const float* __restrict__ cbhh,
                       const float* __restrict__ wbih, const float* __restrict__ wbhh,
                       float* __restrict__ b1, float* __restrict__ bw0, float* __restrict__ bw1) {
  int i = blockIdx.x * blockDim.x + threadIdx.x;
  if (i < 2048) b1[i] = cbih[2048 + i] + cbhh[2048 + i];
  if (i < 4096) {
    bw0[i] = wbih[i] + wbhh[i];
    bw1[i] = wbih[4096 + i] + wbhh[4096 + i];
  }
}

__global__ void k_pre0(const float* __restrict__ Wih0, const float* __restrict__ emb,
                       const float* __restrict__ bih0, const float* __restrict__ bhh0,
                       float* __restrict__ pre0) {
  int wid  = (blockIdx.x * blockDim.x + threadIdx.x) >> 6;
  int lane = threadIdx.x & 63;
  int nw   = (gridDim.x * blockDim.x) >> 6;
  for (int row = wid; row < VCHAR * 2048; row += nw) {
    int c = row >> 11, r = row & 2047;
    float e8[8];
    load8(emb + ((size_t)c << 9), lane, e8);
    const f4* wp = (const f4*)(Wih0 + ((size_t)r << 9) + (lane << 3));
    f4 a = wp[0], b = wp[1];
    float s = a.x*e8[0] + a.y*e8[1] + a.z*e8[2] + a.w*e8[3]
            + b.x*e8[4] + b.y*e8[5] + b.z*e8[6] + b.w*e8[7];
    s = wred(s);
    if (lane == 0) pre0[row] = s + bih0[r] + bhh0[r];
  }
}

__global__ void k_xwg(const int* __restrict__ xwords, const float* __restrict__ glove,
                      const float* __restrict__ gw, const float* __restrict__ gb,
                      float* __restrict__ xw, float* __restrict__ g) {
  __shared__ float red[4];
  int t = blockIdx.x, tid = threadIdx.x;
  const float* row = glove + (size_t)xwords[t] * HWD;
  f4 v = ((const f4*)row)[tid];
  ((f4*)(xw + (size_t)t * HWD))[tid] = v;
  f4 w = ((const f4*)gw)[tid];
  float s = v.x*w.x + v.y*w.y + v.z*w.z + v.w*w.w;
  s = wred(s);
  if ((tid & 63) == 0) red[tid >> 6] = s;
  __syncthreads();
  if (tid == 0) {
    float tot = red[0] + red[1] + red[2] + red[3] + gb[0];
    g[t] = tot > 0.f ? tot : 0.f;
  }
}

// ---------------- the persistent sequential kernel ----------------
struct SeqP {
  const int* x_chars;
  const float* h_char0; const float* c_char0;
  const float* h_word0; const float* c_word0;
  int *ring2, *c1c2, *xg2, *hw02, *hw12;
  float* y;
  const float *gt, *xw, *pre0, *b1, *bw0, *bw1;
  const unsigned short *Whh0, *Wih1, *Whh1, *c2e;
  const unsigned short *wWih0, *wWhh0, *wWih1, *wWhh1;
  float* out;
};

__global__ __launch_bounds__(NTHR) void k_seq(SeqP P) {
  __shared__ float lds_pub[1024];   // {h0[512], h1[512]} of previous round
  __shared__ float lds_a[1024];     // gate: c1c; w0: xg; w1: hw0(new)
  __shared__ float lds_b[1024];     // w0: hw0(old); w1: hw1(old)

  const int tid  = threadIdx.x;
  const int lane = tid & 63;
  const int wv   = tid >> 6;                        // wave 0..3
  const int bid  = blockIdx.x;
  const int wid  = (bid << 2) + wv;                 // 0..255
  const int j0   = wid << 1;   // owns char rows j0, j0+1      (512 total)
  const int m0   = wid << 2;   // owns word rows m0..m0+3      (1024 total)
  const int cst  = (lane + bid) & 63;               // staggered probe chunk

  // cell states live in registers for the whole sequence
  float c0[2], c1[2], cw0[4], cw1[4];
  c0[0] = P.c_char0[j0];       c0[1] = P.c_char0[j0 + 1];
  c1[0] = P.c_char0[512 + j0]; c1[1] = P.c_char0[512 + j0 + 1];
  #pragma unroll
  for (int mm = 0; mm < 4; mm++) {
    cw0[mm] = P.c_word0[m0 + mm];
    cw1[mm] = P.c_word0[1024 + m0 + mm];
  }

  { // init tagged pairs (pair p of slot s = int offset s*2048 + p*2):
    // RING slot 63, pairs 0..511 (h0-part), tag -1   <- read by wave0 at r=0
    // RING slot 0,  pairs 512..1023 (h1-part), tag 0 <- read by wave3 at r=1
    // hw0 slot0 (tag 2), hw1 slot0 (tag 3).
    int g = bid * NTHR + tid;
    if      (g < 512)  st8(P.ring2 + 63 * 2048 + g * 2, P.h_char0[g], -1);
    else if (g < 1024) st8(P.ring2 + g * 2, P.h_char0[g], 0);   // slot0 pair g (h1)
    else if (g < 2048) { int e = g - 1024; st8(P.hw02 + e * 2, P.h_word0[e], 2); }
    else if (g < 3072) { int e = g - 2048; st8(P.hw12 + e * 2, P.h_word0[1024 + e], 3); }
  }
  // no barrier: consumers poll tags.

  // ======== pipelined round loop (no grid barrier — tags are the sync) ========
  // RING(r) base = ring2 + (r & 63)*2048; round r probes RING(r-1).
  for (int r = 0; r < NROUNDS; r++) {
    const bool do_l0 = (r < 4096);
    const bool do_l1 = (r >= 1) && (r <= 4096);
    const bool pubcf = do_l1 && (((r - 1) & 15) == 15);
    const int rg = r - 17, r0w = r - 18, r1w = r - 19;
    const bool do_g  = (rg  >= 0) && ((rg  & 15) == 0);
    const bool do_w0 = (r0w >= 0) && ((r0w & 15) == 0);
    const bool do_w1 = (r1w >= 0) && ((r1w & 15) == 0);
    const int tg = rg >> 4, t0 = r0w >> 4, t1 = r1w >> 4;
    const int rs = (r - 1) & 63;                    // ring slot of round r-1

    // ---- tag-polled staging (waves poll disjoint regions in parallel) ----
    if (wv == 0) {
      if (r <= 4096) {
        float v[8];
        probe512(P.ring2 + rs * 2048, cst, r - 1, v);
        f4* d = (f4*)&lds_pub[cst << 3];
        f4 a; a.x=v[0]; a.y=v[1]; a.z=v[2]; a.w=v[3];
        f4 b; b.x=v[4]; b.y=v[5]; b.z=v[6]; b.w=v[7];
        d[0] = a; d[1] = b;
      }
    } else if (wv == 3) {
      if (r >= 1 && r <= 4096) {
        float v[8];
        probe512(P.ring2 + rs * 2048 + 1024, cst, r - 1, v);
        f4* d = (f4*)&lds_pub[512 + (cst << 3)];
        f4 a; a.x=v[0]; a.y=v[1]; a.z=v[2]; a.w=v[3];
        f4 b; b.x=v[4]; b.y=v[5]; b.z=v[6]; b.w=v[7];
        d[0] = a; d[1] = b;
      }
    } else if (wv == 1) {
      if (do_g) {
        float v[8];
        probe512(P.c1c2, cst, r - 1, v);
        f4* d = (f4*)&lds_a[cst << 3];
        f4 a; a.x=v[0]; a.y=v[1]; a.z=v[2]; a.w=v[3];
        f4 b; b.x=v[4]; b.y=v[5]; b.z=v[6]; b.w=v[7];
        d[0] = a; d[1] = b;
      } else if (do_w0 || do_w1) {
        float v[16];
        const int* base = do_w0 ? P.xg2 : (P.hw02 + ((t1 & 1) ^ 1) * 2048);
        probe1024(base, cst, r - 1, v);
        f4* d = (f4*)&lds_a[cst << 4];
        #pragma unroll
        for (int k = 0; k < 4; k++) {
          f4 a; a.x=v[4*k]; a.y=v[4*k+1]; a.z=v[4*k+2]; a.w=v[4*k+3];
          d[k] = a;
        }
      }
    } else { // wv == 2
      if (do_w0 || do_w1) {
        float v[16];
        const int* base = do_w0 ? (P.hw02 + (t0 & 1) * 2048)
                                : (P.hw12 + (t1 & 1) * 2048);
        probe1024(base, cst, r - 16, v);
        f4* d = (f4*)&lds_b[cst << 4];
        #pragma unroll
        for (int k = 0; k < 4; k++) {
          f4 a; a.x=v[4*k]; a.y=v[4*k+1]; a.z=v[4*k+2]; a.w=v[4*k+3];
          d[k] = a;
        }
      }
    }
    __syncthreads();

    // ---- compute + immediate tagged publication (ring slot r & 63) ----
    float h8[8], b8[8];
    {
      const f4* p0 = (const f4*)&lds_pub[lane << 3];
      f4 v0 = p0[0], v1 = p0[1];
      h8[0]=v0.x; h8[1]=v0.y; h8[2]=v0.z; h8[3]=v0.w;
      h8[4]=v1.x; h8[5]=v1.y; h8[6]=v1.z; h8[7]=v1.w;
      const f4* p1 = (const f4*)&lds_pub[512 + (lane << 3)];
      f4 w0_ = p1[0], w1_ = p1[1];
      b8[0]=w0_.x; b8[1]=w0_.y; b8[2]=w0_.z; b8[3]=w0_.w;
      b8[4]=w1_.x; b8[5]=w1_.y; b8[6]=w1_.z; b8[7]=w1_.w;
    }
    int* ringw = P.ring2 + (r & 63) * 2048;   // RING(r)

    if (do_l0) {   // char layer 0 for cs = r
      const int ci = P.x_chars[r];
      const float* preb = P.pre0 + (size_t)ci * 2048;
      float hv[2];
      #pragma unroll
      for (int jj = 0; jj < 2; jj++) {
        int j = j0 + jj;
        float zi = wred(rowdot512(P.Whh0,        j, h8, lane)) + preb[j];
        float zf = wred(rowdot512(P.Whh0,  512 + j, h8, lane)) + preb[512 + j];
        float zg = wred(rowdot512(P.Whh0, 1024 + j, h8, lane)) + preb[1024 + j];
        float zo = wred(rowdot512(P.Whh0, 1536 + j, h8, lane)) + preb[1536 + j];
        hv[jj] = lstm_cell(zi, zf, zg, zo, c0[jj]);
      }
      if (lane == 0)
        st16(ringw + (bid << 4) + (wv << 2), pk2(hv[0], hv[1], r));
    }

    if (do_l1) {   // char layer 1 for cs = r-1 (input h0(cs=r-1) == h8)
      float hv[2];
      #pragma unroll
      for (int jj = 0; jj < 2; jj++) {
        int j = j0 + jj;
        float z[4];
        #pragma unroll
        for (int gq = 0; gq < 4; gq++) {
          int rr = gq * 512 + j;
          z[gq] = wred(rowdot512(P.Wih1, rr, h8, lane)
                     + rowdot512(P.Whh1, rr, b8, lane)) + P.b1[rr];
        }
        hv[jj] = lstm_cell(z[0], z[1], z[2], z[3], c1[jj]);
      }
      if (lane == 0) {
        st16(ringw + 1024 + (bid << 4) + (wv << 2), pk2(hv[0], hv[1], r));
        if (pubcf) st16(P.c1c2 + (bid << 4) + (wv << 2), pk2(c1[0], c1[1], r));
      }
    }

    if (do_g) {    // gate(t): xg = (1-g)*x_word + g*(c2e @ c1)
      float cg8[8];
      const f4* pc = (const f4*)&lds_a[lane << 3];
      f4 v0 = pc[0], v1 = pc[1];
      cg8[0]=v0.x; cg8[1]=v0.y; cg8[2]=v0.z; cg8[3]=v0.w;
      cg8[4]=v1.x; cg8[5]=v1.y; cg8[6]=v1.z; cg8[7]=v1.w;
      const float gv = P.gt[tg];
      const float* xwrow = P.xw + (size_t)tg * HWD;
      float xv[4];
      #pragma unroll
      for (int mm = 0; mm < 4; mm++) {
        int m = m0 + mm;
        float xc = wred(rowdot512(P.c2e, m, cg8, lane));
        xv[mm] = (1.f - gv) * xwrow[m] + gv * xc;
      }
      if (lane == 0) {
        int* dst = P.xg2 + (bid << 5) + (wv << 3);
        st16(dst,     pk2(xv[0], xv[1], r));
        st16(dst + 4, pk2(xv[2], xv[3], r));
      }
    }

    if (do_w0) {   // word layer 0
      float x16[16], h16[16];
      {
        const f4* pa = (const f4*)&lds_a[lane << 4];
        const f4* pb = (const f4*)&lds_b[lane << 4];
        #pragma unroll
        for (int k = 0; k < 4; k++) {
          f4 va = pa[k], vb = pb[k];
          x16[4*k+0]=va.x; x16[4*k+1]=va.y; x16[4*k+2]=va.z; x16[4*k+3]=va.w;
          h16[4*k+0]=vb.x; h16[4*k+1]=vb.y; h16[4*k+2]=vb.z; h16[4*k+3]=vb.w;
        }
      }
      float hv[4];
      #pragma unroll
      for (int mm = 0; mm < 4; mm++) {
        int m = m0 + mm;
        float z[4];
        #pragma unroll
        for (int gq = 0; gq < 4; gq++) {
          int rr = (gq << 10) + m;
          z[gq] = wred(rowdot1024(P.wWih0, rr, x16, lane)
                     + rowdot1024(P.wWhh0, rr, h16, lane)) + P.bw0[rr];
        }
        hv[mm] = lstm_cell(z[0], z[1], z[2], z[3], cw0[mm]);
      }
      if (lane == 0) {
        int* dst = P.hw02 + ((t0 & 1) ^ 1) * 2048 + (bid << 5) + (wv << 3);
        st16(dst,     pk2(hv[0], hv[1], r));
        st16(dst + 4, pk2(hv[2], hv[3], r));
      }
    }

    if (do_w1) {   // word layer 1 (top output -> y[t])
      float a16[16], b16[16];
      {
        const f4* pa = (const f4*)&lds_a[lane << 4];
        const f4* pb = (const f4*)&lds_b[lane << 4];
        #pragma unroll
        for (int k = 0; k < 4; k++) {
          f4 va = pa[k], vb = pb[k];
          a16[4*k+0]=va.x; a16[4*k+1]=va.y; a16[4*k+2]=va.z; a16[4*k+3]=va.w;
          b16[4*k+0]=vb.x; b16[4*k+1]=vb.y; b16[4*k+2]=vb.z; b16[4*k+3]=vb.w;
        }
      }
      float hv[4];
      #pragma unroll
      for (int mm = 0; mm < 4; mm++) {
        int m = m0 + mm;
        float z[4];
        #pragma unroll
        for (int gq = 0; gq < 4; gq++) {
          int rr = (gq << 10) + m;
          z[gq] = wred(rowdot1024(P.wWih1, rr, a16, lane)
                     + rowdot1024(P.wWhh1, rr, b16, lane)) + P.bw1[rr];
        }
        hv[mm] = lstm_cell(z[0], z[1], z[2], z[3], cw1[mm]);
      }
      if (lane == 0) {
        int* dst = P.hw12 + ((t1 & 1) ^ 1) * 2048 + (bid << 5) + (wv << 3);
        st16(dst,     pk2(hv[0], hv[1], r));
        st16(dst + 4, pk2(hv[2], hv[3], r));
        float* yrow = P.y + (size_t)t1 * HWD;
        yrow[m0]     = hv[0];
        yrow[m0 + 1] = hv[1];
        yrow[m0 + 2] = hv[2];
        yrow[m0 + 3] = hv[3];
      }
    }

    __syncthreads();   // protect LDS buffers before next round's staging
  }

  // ---- epilogue ----
  const size_t LOG = (size_t)T_STEPS * VWORD;
  float* o_hw = P.out + LOG;
  float* o_cw = o_hw + 2048;
  float* o_hc = o_cw + 2048;
  float* o_cc = o_hc + 1024;
  if (lane == 0) {
    o_cc[j0]       = c0[0];  o_cc[j0 + 1]       = c0[1];
    o_cc[512 + j0] = c1[0];  o_cc[512 + j0 + 1] = c1[1];
    #pragma unroll
    for (int mm = 0; mm < 4; mm++) {
      o_cw[m0 + mm]        = cw0[mm];
      o_cw[1024 + m0 + mm] = cw1[mm];
    }
  }
  if (bid == 0) {
    // final h: h0 tag 4095 in RING slot 63 pairs 0..511; h1 tag 4096 in slot 0
    // pairs 512..1023; hw0 tag 4098 (slot0); hw1 tag 4099 (slot0).
    for (int i = tid; i < 512; i += NTHR) {
      o_hc[i]       = pollpair(P.ring2 + 63 * 2048 + i * 2, 4095);
      o_hc[512 + i] = pollpair(P.ring2 + (512 + i) * 2, 4096);
    }
    for (int i = tid; i < 1024; i += NTHR) {
      o_hw[i]        = pollpair(P.hw02 + i * 2, 4098);
      o_hw[1024 + i] = pollpair(P.hw12 + i * 2, 4099);
    }
  }
}

// ---------------- decoder GEMM: logits[256][50257] = y @ dec_W^T + dec_b (f32) ----------------
__global__ __launch_bounds__(256) void k_decoder(const float* __restrict__ y,
                                                 const float* __restrict__ W,
                                                 const float* __restrict__ bias,
                                                 float* __restrict__ out) {
  __shared__ float As[32][65];
  __shared__ float Bs[32][65];
  const int tid = threadIdx.x;
  const int v0 = blockIdx.x * 64;
  const int t0 = blockIdx.y * 64;
  const int tx = tid & 15, ty = tid >> 4;
  float acc[4][4] = {};
  for (int k0 = 0; k0 < 1024; k0 += 32) {
    #pragma unroll
    for (int e = 0; e < 2; e++) {
      int fi = tid * 2 + e;
      int rr = fi >> 3;
      int kk = (fi & 7) << 2;
      f4 av = *(const f4*)(y + (size_t)(t0 + rr) * 1024 + k0 + kk);
      As[kk][rr] = av.x; As[kk+1][rr] = av.y; As[kk+2][rr] = av.z; As[kk+3][rr] = av.w;
      int vg = v0 + rr;
      f4 bv;
      if (vg < VWORD) bv = *(const f4*)(W + (size_t)vg * 1024 + k0 + kk);
      else { bv.x = 0.f; bv.y = 0.f; bv.z = 0.f; bv.w = 0.f; }
      Bs[kk][rr] = bv.x; Bs[kk+1][rr] = bv.y; Bs[kk+2][rr] = bv.z; Bs[kk+3][rr] = bv.w;
    }
    __syncthreads();
    #pragma unroll
    for (int kk = 0; kk < 32; kk++) {
      float a[4], b[4];
      #pragma unroll
      for (int i = 0; i < 4; i++) a[i] = As[kk][ty * 4 + i];
      #pragma unroll
      for (int j = 0; j < 4; j++) b[j] = Bs[kk][tx * 4 + j];
      #pragma unroll
      for (int i = 0; i < 4; i++)
        #pragma unroll
        for (int j = 0; j < 4; j++) acc[i][j] += a[i] * b[j];
    }
    __syncthreads();
  }
  #pragma unroll
  for (int i = 0; i < 4; i++) {
    int t = t0 + ty * 4 + i;
    #pragma unroll
    for (int j = 0; j < 4; j++) {
      int v = v0 + tx * 4 + j;
      if (v < VWORD) out[(size_t)t * VWORD + v] = acc[i][j] + bias[v];
    }
  }
}

// ---------------- host launch ----------------
extern "C" void kernel_launch(void* const* d_in, const int* in_sizes, int n_in,
                              void* d_out, int out_size, void* d_ws, size_t ws_size,
                              hipStream_t stream) {
  const int*   x_words  = (const int*)d_in[0];
  const int*   x_chars  = (const int*)d_in[1];
  const float* h_word0  = (const float*)d_in[2];
  const float* c_word0  = (const float*)d_in[3];
  const float* h_char0  = (const float*)d_in[4];
  const float* c_char0  = (const float*)d_in[5];
  const float* glove    = (const float*)d_in[6];
  const float* char_emb = (const float*)d_in[7];
  const float* char_Wih = (const float*)d_in[8];
  const float* char_Whh = (const float*)d_in[9];
  const float* char_bih = (const float*)d_in[10];
  const float* char_bhh = (const float*)d_in[11];
  const float* word_Wih = (const float*)d_in[12];
  const float* word_Whh = (const float*)d_in[13];
  const float* word_bih = (const float*)d_in[14];
  const float* word_bhh = (const float*)d_in[15];
  const float* c2e      = (const float*)d_in[16];
  const float* g_w      = (const float*)d_in[17];
  const float* g_b      = (const float*)d_in[18];
  const float* dec_W    = (const float*)d_in[19];
  const float* dec_b    = (const float*)d_in[20];

  float* out = (float*)d_out;
  float* ws  = (float*)d_ws;
  int*   wsi = (int*)d_ws;
  unsigned short* bfb = (unsigned short*)(ws + WS_BF);

  // re-poison ALL exchange tags each launch (0xAA never equals a valid tag)
  hipMemsetAsync(wsi, 0xAA, I_END * sizeof(int), stream);

  k_convert<<<1024, 256, 0, stream>>>(char_Whh,                       bfb + BF_CHH0, 2048 * 512);
  k_convert<<<1024, 256, 0, stream>>>(char_Wih + (size_t)2048 * 512,  bfb + BF_CIH1, 2048 * 512);
  k_convert<<<1024, 256, 0, stream>>>(char_Whh + (size_t)2048 * 512,  bfb + BF_CHH1, 2048 * 512);
  k_convert<<<1024, 256, 0, stream>>>(c2e,                            bfb + BF_C2E,  1024 * 512);
  k_convert<<<2048, 256, 0, stream>>>(word_Wih,                       bfb + BF_WIH0, 4096 * 1024);
  k_convert<<<2048, 256, 0, stream>>>(word_Whh,                       bfb + BF_WHH0, 4096 * 1024);
  k_convert<<<2048, 256, 0, stream>>>(word_Wih + (size_t)4096 * 1024, bfb + BF_WIH1, 4096 * 1024);
  k_convert<<<2048, 256, 0, stream>>>(word_Whh + (size_t)4096 * 1024, bfb + BF_WHH1, 4096 * 1024);
  k_bias<<<16, 256, 0, stream>>>(char_bih, char_bhh, word_bih, word_bhh,
                                 ws + WS_B1, ws + WS_BW0, ws + WS_BW1);
  k_pre0<<<256, 256, 0, stream>>>(char_Wih, char_emb, char_bih, char_bhh, ws + WS_PRE0);
  k_xwg<<<256, 256, 0, stream>>>(x_words, glove, g_w, g_b, ws + WS_XW, ws + WS_G);

  SeqP P;
  P.x_chars = x_chars;
  P.h_char0 = h_char0;  P.c_char0 = c_char0;
  P.h_word0 = h_word0;  P.c_word0 = c_word0;
  P.ring2 = wsi + I_RING;  P.c1c2 = wsi + I_C1C;  P.xg2 = wsi + I_XG;
  P.hw02 = wsi + I_HW0;  P.hw12 = wsi + I_HW1;
  P.y   = ws + WS_Y;
  P.gt  = ws + WS_G;    P.xw  = ws + WS_XW;   P.pre0 = ws + WS_PRE0;
  P.b1  = ws + WS_B1;   P.bw0 = ws + WS_BW0;  P.bw1 = ws + WS_BW1;
  P.Whh0 = bfb + BF_CHH0;  P.Wih1 = bfb + BF_CIH1;  P.Whh1 = bfb + BF_CHH1;
  P.c2e  = bfb + BF_C2E;
  P.wWih0 = bfb + BF_WIH0;  P.wWhh0 = bfb + BF_WHH0;
  P.wWih1 = bfb + BF_WIH1;  P.wWhh1 = bfb + BF_WHH1;
  P.out = out;

  k_seq<<<NWG, NTHR, 0, stream>>>(P);

  k_decoder<<<dim3((VWORD + 63) / 64, 4), 256, 0, stream>>>(ws + WS_Y, dec_W, dec_b, out);
}